// Round 11
// baseline (390.167 us; speedup 1.0000x reference)
//
#include <hip/hip_runtime.h>
#include <math.h>

// ---------------------------------------------------------------------------
// GAT 3-layer net. R11 = R10 + attention dots folded into the GEMM as 16
// extra weight columns (exact math: als = X @ (W @ a_s_blockvec)):
//  - k_prep computes w_als/w_ald panels (rows 2048-2055 of Wc1/Wc2, bf16),
//    zeroes rows 2056-2175; GEMM runs 17 n-tiles; tile 16's epilogue writes
//    als/ald fp32 directly. k_attn_dots deleted.
//  - R10 parts kept: fp8 H, fused attn3, XOR LDS swizzle (0 conflicts),
//    BK=64 128x128 GEMM, XCD swizzle, mega-prep.
// ---------------------------------------------------------------------------

__device__ __forceinline__ float leaky(float x){ return x > 0.f ? x : 0.2f * x; }

__device__ __forceinline__ float bf2f(unsigned short u){
  union { unsigned int i; float f; } v; v.i = ((unsigned int)u) << 16; return v.f;
}
__device__ __forceinline__ unsigned short f2bf(float f){
  union { float f; unsigned int i; } v; v.f = f;
  unsigned int r = v.i + 0x7FFF + ((v.i >> 16) & 1);   // RNE
  return (unsigned short)(r >> 16);
}
__device__ __forceinline__ float4 loadbf4(const unsigned short* p){
  ushort4 u = *(const ushort4*)p;
  return make_float4(bf2f(u.x), bf2f(u.y), bf2f(u.z), bf2f(u.w));
}

// ---- fp8 e4m3 helpers (HW cvt; self-consistent round-trip) ----
typedef __attribute__((ext_vector_type(2))) float f2v;
__device__ __forceinline__ unsigned char f2fp8(float x){
  int v = __builtin_amdgcn_cvt_pk_fp8_f32(x, x, 0, false);
  return (unsigned char)(v & 0xff);
}
__device__ __forceinline__ float4 fp8x4(unsigned int u){
  f2v a = __builtin_amdgcn_cvt_pk_f32_fp8((int)u, false);
  f2v b = __builtin_amdgcn_cvt_pk_f32_fp8((int)u, true);
  return make_float4(a.x, a.y, b.x, b.y);
}

// ---------------- mega prep kernel ----------------
__device__ __forceinline__ void tr_tile(const float* __restrict__ W,
                                        unsigned short* __restrict__ Wt,
                                        int K, int N, int rowOff, int lb,
                                        unsigned short tile[32][33]){
  int gx = K >> 5;
  int bk = (lb % gx) << 5;
  int bn = (lb / gx) << 5;
  int tx = threadIdx.x & 31;
  int ty = threadIdx.x >> 5;
#pragma unroll
  for (int r = 0; r < 32; r += 8)
    tile[ty + r][tx] = f2bf(W[(size_t)(bk + ty + r) * N + bn + tx]);
  __syncthreads();
#pragma unroll
  for (int r = 0; r < 32; r += 8)
    Wt[(size_t)(rowOff + bn + ty + r) * K + bk + tx] = tile[tx][ty + r];
}

// segments (256 thr/block):
//  s0..s3: weight transposes; s4: w3fill; s5: attn-col dots (48 blocks);
//  s6: Wc1 rows 2056-2175 zero (60); s7: Wc2 rows 2056-2175 zero (120);
//  s8: nf cvt_pad (Mpad/2); s9: Abf2 pad zero (Mpad-N); s10: degree count.
__global__ __launch_bounds__(256) void k_prep(
    const float* __restrict__ W1, const float* __restrict__ Wl1,
    const float* __restrict__ W2, const float* __restrict__ Wl2,
    const float* __restrict__ W3, const float* __restrict__ Wl3,
    const float* __restrict__ bl3,
    const float* __restrict__ as1, const float* __restrict__ ad1,
    const float* __restrict__ as2, const float* __restrict__ ad2,
    const float* __restrict__ nf, const int* __restrict__ ei,
    unsigned short* __restrict__ Wc1, unsigned short* __restrict__ Wc2,
    unsigned short* __restrict__ Bt3, float* __restrict__ biasc,
    unsigned short* __restrict__ Abf1, unsigned short* __restrict__ Abf2,
    int* __restrict__ deg, int Mpad, int N, int E)
{
  __shared__ unsigned short tile[32][33];
  int lb = blockIdx.x;
  if (lb < 512){ tr_tile(W1, Wc1, 512, 1024, 0, lb, tile); return; }
  lb -= 512;
  if (lb < 512){ tr_tile(Wl1, Wc1, 512, 1024, 1024, lb, tile); return; }
  lb -= 512;
  if (lb < 1024){ tr_tile(W2, Wc2, 1024, 1024, 0, lb, tile); return; }
  lb -= 1024;
  if (lb < 1024){ tr_tile(Wl2, Wc2, 1024, 1024, 1024, lb, tile); return; }
  lb -= 1024;
  if (lb < 512){              // w3fill: Bt3[128][1024] + biasc[48]
    int idx = lb * 256 + threadIdx.x;
    if (idx < 48) biasc[idx] = (idx >= 36 && idx < 42) ? bl3[idx - 36] : 0.f;
    int n = idx >> 10, k = idx & 1023;
    float v = 0.f;
    if (n < 36) v = W3[(size_t)k * 36 + n];
    else if (n < 42) v = Wl3[(size_t)k * 6 + (n - 36)];
    Bt3[idx] = f2bf(v);
    return;
  }
  lb -= 512;
  if (lb < 48){               // attention-column dots
    int id = lb * 256 + threadIdx.x;     // 0..12287
    if (id < 4096){
      int h = id & 3, sd = (id >> 2) & 1, k = id >> 3;      // k 0..511
      const float* av = sd ? ad1 : as1;
      float s = 0.f;
#pragma unroll 4
      for (int c = 0; c < 256; c++)
        s += W1[(size_t)k * 1024 + h * 256 + c] * av[h * 256 + c];
      Wc1[(size_t)(2048 + sd * 4 + h) * 512 + k] = f2bf(s);
    } else {
      int id2 = id - 4096;
      int h = id2 & 3, sd = (id2 >> 2) & 1, k = id2 >> 3;   // k 0..1023
      const float* av = sd ? ad2 : as2;
      float s = 0.f;
#pragma unroll 4
      for (int c = 0; c < 256; c++)
        s += W2[(size_t)k * 1024 + h * 256 + c] * av[h * 256 + c];
      Wc2[(size_t)(2048 + sd * 4 + h) * 1024 + k] = f2bf(s);
    }
    return;
  }
  lb -= 48;
  if (lb < 60){               // zero Wc1 rows 2056-2175 (120*512 ushorts)
    int idx = lb * 256 + threadIdx.x;    // ushort4 units, 15360 total
    ushort4 z; z.x = z.y = z.z = z.w = 0;
    *(ushort4*)(Wc1 + (size_t)2056 * 512 + (size_t)idx * 4) = z;
    return;
  }
  lb -= 60;
  if (lb < 120){              // zero Wc2 rows 2056-2175 (120*1024 ushorts)
    int idx = lb * 256 + threadIdx.x;    // 30720 ushort4
    ushort4 z; z.x = z.y = z.z = z.w = 0;
    *(ushort4*)(Wc2 + (size_t)2056 * 1024 + (size_t)idx * 4) = z;
    return;
  }
  lb -= 120;
  int cvtBlocks = Mpad >> 1;
  if (lb < cvtBlocks){        // nf fp32 [N,512] -> Abf1 bf16 [Mpad,512]
    int idx = lb * 256 + threadIdx.x;
    int e = idx << 2;
    int row = e >> 9;
    ushort4 o;
    if (row < N){
      float4 v = *(const float4*)(nf + (size_t)row * 512 + (e & 511));
      o.x = f2bf(v.x); o.y = f2bf(v.y); o.z = f2bf(v.z); o.w = f2bf(v.w);
    } else { o.x = o.y = o.z = o.w = 0; }
    *(ushort4*)(Abf1 + e) = o;
    return;
  }
  lb -= cvtBlocks;
  int padBlocks = Mpad - N;
  if (lb < padBlocks){        // zero Abf2 rows N..Mpad
    int idx = lb * 256 + threadIdx.x;
    ushort4 z; z.x = z.y = z.z = z.w = 0;
    *(ushort4*)(Abf2 + (size_t)N * 1024 + (size_t)idx * 4) = z;
    return;
  }
  lb -= padBlocks;
  int e = lb * 256 + threadIdx.x;   // degree count
  if (e < E) atomicAdd(&deg[ei[E + e]], 1);
}

// ---------------- CSR scan + scatter ----------------
__global__ void k_scan(const int* __restrict__ deg, int* __restrict__ rp,
                       int* __restrict__ cur, int n){
  __shared__ int part[1024];
  int t = threadIdx.x;
  int K = (n + 1023) >> 10;
  int vals[16];
  int start = t * K;
  int local = 0;
  for (int j = 0; j < K; j++){
    int idx = start + j;
    int v = (idx < n) ? deg[idx] : 0;
    vals[j] = local;
    local += v;
  }
  part[t] = local;
  __syncthreads();
  for (int off = 1; off < 1024; off <<= 1){
    int v = (t >= off) ? part[t - off] : 0;
    __syncthreads();
    part[t] += v;
    __syncthreads();
  }
  int base = part[t] - local;
  for (int j = 0; j < K; j++){
    int idx = start + j;
    if (idx < n){ rp[idx] = base + vals[j]; cur[idx] = base + vals[j]; }
  }
  if (t == 1023) rp[n] = part[1023];
}

__global__ void k_scatter(const int* __restrict__ ei, int* __restrict__ cur,
                          int* __restrict__ col, int E){
  int e = blockIdx.x * blockDim.x + threadIdx.x;
  if (e < E){
    int s = ei[e], d = ei[E + e];
    int p = atomicAdd(&cur[d], 1);
    col[p] = s;
  }
}

// ---------------- bf16 MFMA GEMM, 128x128 tile, BK=64, LDS XOR swizzle ------
typedef __attribute__((ext_vector_type(8))) short bf8_t;
typedef __attribute__((ext_vector_type(4))) float f4_t;

__device__ __forceinline__ void async16(const unsigned short* g, unsigned short* l){
  __builtin_amdgcn_global_load_lds(
      (const __attribute__((address_space(1))) void*)g,
      (__attribute__((address_space(3))) void*)l, 16, 0, 0);
}

// grid: 8 * Gm * nTiles (1D); xcd = b&7 owns m-tiles [xcd*Gm, ...)
// fpOut=0 (layers 1/2, 17 n-tiles): bn<1024 -> outH fp8;
//   1024<=bn<2048 -> outY bf16 + bias[colg-1024];
//   bn==2048 -> cols 0-3: als[row*4+c], cols 4-7: ald[row*4+(c-4)] (fp32).
// fpOut=1 (layer 3, Ntot=48): outF fp32 + bias; fused attn3 dots via LDS.
__global__ __launch_bounds__(256) void k_mfma_gemm(
    const unsigned short* __restrict__ A,
    const unsigned short* __restrict__ Bt,
    const float* __restrict__ bias,
    unsigned char* __restrict__ outH,
    unsigned short* __restrict__ outY,
    float* __restrict__ outF,
    const float* __restrict__ as3, const float* __restrict__ ad3,
    float* __restrict__ als, float* __restrict__ ald,
    int M, int K, int Ntot, int Mtiles, int Gm, int fpOut)
{
  __shared__ unsigned short SM[2 * 8192];        // 32 KB total
  unsigned short* Asm = SM;                      // 16 KB (two 32-k planes)
  unsigned short* Bsm = SM + 8192;               // 16 KB
  int b = blockIdx.x;
  int xcd = b & 7;
  int j = b >> 3;
  int mloc = j % Gm;
  int n = j / Gm;
  int mtile = xcd * Gm + mloc;
  if (mtile >= Mtiles) return;
  int bm = mtile * 128, bn = n * 128;

  int t = threadIdx.x;
  int w = t >> 6, lane = t & 63;
  int wm = (w >> 1) * 64, wn = (w & 1) * 64;
  int lr = lane & 15, lq = lane >> 4;

  f4_t acc[4][4] = {};

  int srow = lane >> 2;                                   // 0..15 in chunk
  int scol = (((lane & 3) ^ ((lane >> 3) & 3)) << 3);     // swizzled k-chunk
  int sw   = (lr >> 1) & 3;                               // read-side swizzle

  for (int k0 = 0; k0 < K; k0 += 64){
#pragma unroll
    for (int h = 0; h < 2; h++){
#pragma unroll
      for (int r = 0; r < 2; r++){
        int c = r * 4 + w;
        async16(A + (size_t)(bm + c * 16 + srow) * K + k0 + h * 32 + scol,
                &Asm[h * 4096 + c * 512]);
        async16(Bt + (size_t)(bn + c * 16 + srow) * K + k0 + h * 32 + scol,
                &Bsm[h * 4096 + c * 512]);
      }
    }
    __syncthreads();
#pragma unroll
    for (int h = 0; h < 2; h++){
      bf8_t a[4], bfr[4];
#pragma unroll
      for (int i = 0; i < 4; i++)
        a[i] = *(const bf8_t*)&Asm[h * 4096 + (wm + i * 16 + lr) * 32 + (lq ^ sw) * 8];
#pragma unroll
      for (int i = 0; i < 4; i++)
        bfr[i] = *(const bf8_t*)&Bsm[h * 4096 + (wn + i * 16 + lr) * 32 + (lq ^ sw) * 8];
#pragma unroll
      for (int mi = 0; mi < 4; mi++)
#pragma unroll
        for (int ni = 0; ni < 4; ni++)
          acc[mi][ni] = __builtin_amdgcn_mfma_f32_16x16x32_bf16(a[mi], bfr[ni], acc[mi][ni], 0, 0, 0);
    }
    __syncthreads();
  }

  if (fpOut){
    // layer 3: bn==0, Ntot=48. Stage rows into LDS (stride 49) for fused dots.
    float* cl = (float*)SM;
#pragma unroll
    for (int mi = 0; mi < 4; mi++){
#pragma unroll
      for (int ni = 0; ni < 4; ni++){
        int colg = wn + ni * 16 + lr;
        if (colg >= Ntot) continue;
        float bv = bias[colg];
#pragma unroll
        for (int rg = 0; rg < 4; rg++){
          int rowl = wm + mi * 16 + lq * 4 + rg;
          int rowg = bm + rowl;
          float v = acc[mi][ni][rg] + bv;
          cl[rowl * 49 + colg] = v;
          if (rowg < M) outF[(size_t)rowg * Ntot + colg] = v;
        }
      }
    }
    __syncthreads();
    for (int task = t; task < 128 * 6; task += 256){
      int row = task / 6, h = task - row * 6;
      int rowg = bm + row;
      if (rowg < M){
        float s = 0.f, d = 0.f;
#pragma unroll
        for (int c = 0; c < 6; c++){
          float v = cl[row * 49 + h * 6 + c];
          s += v * as3[h * 6 + c];
          d += v * ad3[h * 6 + c];
        }
        als[rowg * 6 + h] = s;
        ald[rowg * 6 + h] = d;
      }
    }
  } else if (bn < 1024){
    // H half -> fp8
#pragma unroll
    for (int mi = 0; mi < 4; mi++){
#pragma unroll
      for (int ni = 0; ni < 4; ni++){
        int colg = bn + wn + ni * 16 + lr;
#pragma unroll
        for (int rg = 0; rg < 4; rg++){
          int rowg = bm + wm + mi * 16 + lq * 4 + rg;
          if (rowg < M) outH[(size_t)rowg * 1024 + colg] = f2fp8(acc[mi][ni][rg]);
        }
      }
    }
  } else if (bn < 2048){
    // Y half -> bf16 + bias
#pragma unroll
    for (int mi = 0; mi < 4; mi++){
#pragma unroll
      for (int ni = 0; ni < 4; ni++){
        int colg = bn + wn + ni * 16 + lr - 1024;
        float bv = bias[colg];
#pragma unroll
        for (int rg = 0; rg < 4; rg++){
          int rowg = bm + wm + mi * 16 + lq * 4 + rg;
          if (rowg < M) outY[(size_t)rowg * 1024 + colg] = f2bf(acc[mi][ni][rg] + bv);
        }
      }
    }
  } else {
    // attention-dot tile: local cols 0-3 -> als, 4-7 -> ald
#pragma unroll
    for (int mi = 0; mi < 4; mi++){
#pragma unroll
      for (int ni = 0; ni < 4; ni++){
        int c = wn + ni * 16 + lr;     // 0..127 within tile
        if (c >= 8) continue;
#pragma unroll
        for (int rg = 0; rg < 4; rg++){
          int rowg = bm + wm + mi * 16 + lq * 4 + rg;
          if (rowg < M){
            float v = acc[mi][ni][rg];
            if (c < 4) als[rowg * 4 + c] = v;
            else       ald[rowg * 4 + (c - 4)] = v;
          }
        }
      }
    }
  }
}

// ---------------- GAT aggregation (layers 1/2): fp8 H gather + bf16 Y ------
__global__ __launch_bounds__(256) void k_agg(const unsigned char* __restrict__ Hq,
                                             const unsigned short* __restrict__ Y,
                                             unsigned short* __restrict__ Yout,
                                             const float* __restrict__ bias,
                                             const float* __restrict__ als,
                                             const float* __restrict__ ald,
                                             const int* __restrict__ rp,
                                             const int* __restrict__ col){
  int i = blockIdx.x;
  int t = threadIdx.x;
  int lane = t & 63;
  int w = t >> 6;
  int ro = rp[i];
  int deg = rp[i + 1] - ro;
  __shared__ float sm[4], ss[4];
  __shared__ float s_alpha[64][4];
  __shared__ int s_src[64];

  float aldw = ald[i * 4 + w];
  float eself = leaky(als[i * 4 + w] + aldw);
  float m = eself;
  float s = (lane == 0) ? 1.f : 0.f;
  for (int e = lane; e < deg; e += 64){
    int src = col[ro + e];
    float ev = leaky(als[src * 4 + w] + aldw);
    float M = fmaxf(m, ev);
    s = s * __expf(m - M) + __expf(ev - M);
    m = M;
  }
#pragma unroll
  for (int off = 32; off >= 1; off >>= 1){
    float mo = __shfl_down(m, off);
    float so = __shfl_down(s, off);
    float M = fmaxf(m, mo);
    s = s * __expf(m - M) + so * __expf(mo - M);
    m = M;
  }
  if (lane == 0){ sm[w] = m; ss[w] = s; }
  __syncthreads();

  int head = t >> 6;
  float mh = sm[head];
  float inv = 1.f / (ss[head] + 1e-16f);
  float4 acc = loadbf4(Y + (size_t)i * 1024 + t * 4);
  float4 bb  = *(const float4*)(bias + t * 4);
  acc.x += bb.x; acc.y += bb.y; acc.z += bb.z; acc.w += bb.w;
  float aself = __expf(leaky(als[i * 4 + head] + ald[i * 4 + head]) - mh) * inv;
  {
    float4 hv = fp8x4(*(const unsigned int*)(Hq + (size_t)i * 1024 + t * 4));
    acc.x += aself * hv.x; acc.y += aself * hv.y;
    acc.z += aself * hv.z; acc.w += aself * hv.w;
  }
  for (int base = 0; base < deg; base += 64){
    __syncthreads();
    if (t < 64 && base + t < deg){
      int src = col[ro + base + t];
      s_src[t] = src;
#pragma unroll
      for (int hh = 0; hh < 4; hh++){
        s_alpha[t][hh] = __expf(leaky(als[src * 4 + hh] + ald[i * 4 + hh]) - sm[hh])
                         / (ss[hh] + 1e-16f);
      }
    }
    __syncthreads();
    int nn = min(64, deg - base);
    for (int e = 0; e < nn; e++){
      float a = s_alpha[e][head];
      float4 hv = fp8x4(*(const unsigned int*)(Hq + (size_t)s_src[e] * 1024 + t * 4));
      acc.x += a * hv.x; acc.y += a * hv.y; acc.z += a * hv.z; acc.w += a * hv.w;
    }
  }
  acc.x = acc.x > 0.f ? acc.x : expm1f(acc.x);
  acc.y = acc.y > 0.f ? acc.y : expm1f(acc.y);
  acc.z = acc.z > 0.f ? acc.z : expm1f(acc.z);
  acc.w = acc.w > 0.f ? acc.w : expm1f(acc.w);
  ushort4 o;
  o.x = f2bf(acc.x); o.y = f2bf(acc.y); o.z = f2bf(acc.z); o.w = f2bf(acc.w);
  *(ushort4*)(Yout + (size_t)i * 1024 + t * 4) = o;
}

// ---------------- layer 3: GAT(mean heads) + b3 + lin3 + log_softmax ----------------
__global__ __launch_bounds__(64) void k_layer3(const float* __restrict__ comb,
                                               const float* __restrict__ als,
                                               const float* __restrict__ ald,
                                               const float* __restrict__ b3,
                                               const int* __restrict__ rp,
                                               const int* __restrict__ col,
                                               float* __restrict__ out){
  int i = blockIdx.x;
  int lane = threadIdx.x;
  int ro = rp[i], deg = rp[i + 1] - ro;
  float aldv[6], m[6], s[6];
#pragma unroll
  for (int h = 0; h < 6; h++){
    aldv[h] = ald[i * 6 + h];
    float e = leaky(als[i * 6 + h] + aldv[h]);
    m[h] = e;
    s[h] = (lane == 0) ? 1.f : 0.f;
  }
  for (int e = lane; e < deg; e += 64){
    int src = col[ro + e];
#pragma unroll
    for (int h = 0; h < 6; h++){
      float ev = leaky(als[src * 6 + h] + aldv[h]);
      float M = fmaxf(m[h], ev);
      s[h] = s[h] * __expf(m[h] - M) + __expf(ev - M);
      m[h] = M;
    }
  }
#pragma unroll
  for (int off = 32; off >= 1; off >>= 1){
#pragma unroll
    for (int h = 0; h < 6; h++){
      float mo = __shfl_down(m[h], off);
      float so = __shfl_down(s[h], off);
      float M = fmaxf(m[h], mo);
      s[h] = s[h] * __expf(m[h] - M) + so * __expf(mo - M);
      m[h] = M;
    }
  }
#pragma unroll
  for (int h = 0; h < 6; h++){ m[h] = __shfl(m[h], 0); s[h] = __shfl(s[h], 0); }

  __shared__ float o36[36];
  __shared__ float o6[6];
  if (lane < 36){
    int hh = lane / 6, cc = lane - hh * 6;
    float inv = 1.f / (s[hh] + 1e-16f);
    float acc = __expf(leaky(als[i * 6 + hh] + aldv[hh]) - m[hh]) * inv
                * comb[(size_t)i * 48 + hh * 6 + cc];
    for (int e = 0; e < deg; e++){
      int src = col[ro + e];
      float a = __expf(leaky(als[src * 6 + hh] + aldv[hh]) - m[hh]) * inv;
      acc += a * comb[(size_t)src * 48 + hh * 6 + cc];
    }
    o36[lane] = acc;
  }
  __syncthreads();
  if (lane < 6){
    float v = 0.f;
#pragma unroll
    for (int h = 0; h < 6; h++) v += o36[h * 6 + lane];
    o6[lane] = v * (1.f / 6.f) + b3[lane] + comb[(size_t)i * 48 + 36 + lane];
  }
  __syncthreads();
  if (lane == 0){
    float mx = o6[0];
    for (int c = 1; c < 6; c++) mx = fmaxf(mx, o6[c]);
    float se = 0.f;
    for (int c = 0; c < 6; c++) se += __expf(o6[c] - mx);
    float lse = logf(se);
    for (int c = 0; c < 6; c++) out[(size_t)i * 6 + c] = o6[c] - mx - lse;
  }
}

// ---------------------------------------------------------------------------
extern "C" void kernel_launch(void* const* d_in, const int* in_sizes, int n_in,
                              void* d_out, int out_size, void* d_ws, size_t ws_size,
                              hipStream_t stream){
  const float* nf  = (const float*)d_in[0];
  const int*   ei  = (const int*)d_in[1];
  const float* W1  = (const float*)d_in[2];
  const float* as1 = (const float*)d_in[3];
  const float* ad1 = (const float*)d_in[4];
  const float* b1  = (const float*)d_in[5];
  const float* Wl1 = (const float*)d_in[6];
  const float* bl1 = (const float*)d_in[7];
  const float* W2  = (const float*)d_in[8];
  const float* as2 = (const float*)d_in[9];
  const float* ad2 = (const float*)d_in[10];
  const float* b2  = (const float*)d_in[11];
  const float* Wl2 = (const float*)d_in[12];
  const float* bl2 = (const float*)d_in[13];
  const float* W3  = (const float*)d_in[14];
  const float* as3 = (const float*)d_in[15];
  const float* ad3 = (const float*)d_in[16];
  const float* b3  = (const float*)d_in[17];
  const float* Wl3 = (const float*)d_in[18];
  const float* bl3 = (const float*)d_in[19];
  float* out = (float*)d_out;

  const int N = in_sizes[0] / 512;   // 10000
  const int E = in_sizes[1] / 2;     // 160000
  const int Mpad = ((N + 127) / 128) * 128;   // 10112
  const int Mtiles = Mpad / 128;              // 79
  const int Gm = (Mtiles + 7) / 8;            // 10

  char* ws = (char*)d_ws;
  size_t off = 0;
  auto alloc = [&](size_t bytes) -> char* {
    char* p = ws + off;
    off += (bytes + 255) & ~(size_t)255;
    return p;
  };
  unsigned short* Abf1 = (unsigned short*)alloc((size_t)Mpad * 512 * 2);
  unsigned short* Abf2 = (unsigned short*)alloc((size_t)Mpad * 1024 * 2);
  unsigned char*  Hq   = (unsigned char*)alloc((size_t)N * 1024);
  unsigned short* Ybf  = (unsigned short*)alloc((size_t)N * 1024 * 2);
  float* comb   = (float*)alloc((size_t)N * 48 * 4);
  float* als    = (float*)alloc((size_t)N * 8 * 4);
  float* ald    = (float*)alloc((size_t)N * 8 * 4);
  float* biasc  = (float*)alloc(48 * 4);
  int* deg      = (int*)alloc((size_t)N * 4);
  int* rp       = (int*)alloc((size_t)(N + 1) * 4);
  int* cur      = (int*)alloc((size_t)N * 4);
  int* colx     = (int*)alloc((size_t)E * 4);
  unsigned short* Wc1 = (unsigned short*)alloc((size_t)2176 * 512 * 2);   // 17 tiles
  unsigned short* Wc2 = (unsigned short*)alloc((size_t)2176 * 1024 * 2);
  unsigned short* Bt3 = (unsigned short*)alloc((size_t)128 * 1024 * 2);

  hipMemsetAsync(deg, 0, (size_t)N * 4, stream);

  int prepBlocks = 512 + 512 + 1024 + 1024 + 512 + 48 + 60 + 120
                 + (Mpad >> 1) + (Mpad - N) + (E + 255) / 256;
  k_prep<<<prepBlocks, 256, 0, stream>>>(W1, Wl1, W2, Wl2, W3, Wl3, bl3,
                                         as1, ad1, as2, ad2,
                                         nf, ei, Wc1, Wc2, Bt3, biasc,
                                         Abf1, Abf2, deg, Mpad, N, E);
  k_scan   <<<1, 1024, 0, stream>>>(deg, rp, cur, N);
  k_scatter<<<(E + 255) / 256, 256, 0, stream>>>(ei, cur, colx, E);

  int blocksL = 8 * Gm * 17;   // 16 output tiles + 1 attention-dot tile
  int blocks3 = 8 * Gm * 1;

  // layer 1 (dots fused as GEMM columns)
  k_mfma_gemm<<<blocksL, 256, 0, stream>>>(Abf1, Wc1, bl1, Hq, Ybf, nullptr,
                                           nullptr, nullptr, als, ald,
                                           N, 512, 2176, Mtiles, Gm, 0);
  k_agg<<<N, 256, 0, stream>>>(Hq, Ybf, Abf2, b1, als, ald, rp, colx);

  // layer 2
  k_mfma_gemm<<<blocksL, 256, 0, stream>>>(Abf2, Wc2, bl2, Hq, Ybf, nullptr,
                                           nullptr, nullptr, als, ald,
                                           N, 1024, 2176, Mtiles, Gm, 0);
  k_agg<<<N, 256, 0, stream>>>(Hq, Ybf, Abf2, b2, als, ald, rp, colx);

  // layer 3 (attn3 fused into GEMM epilogue)
  k_mfma_gemm<<<blocks3, 256, 0, stream>>>(Abf2, Bt3, biasc, nullptr, nullptr, comb,
                                           as3, ad3, als, ald,
                                           N, 1024, 48, Mtiles, Gm, 1);
  k_layer3<<<N, 64, 0, stream>>>(comb, als, ald, b3, rp, colx, out);
}

// Round 12
// 371.994 us; speedup vs baseline: 1.0489x; 1.0489x over previous
//
#include <hip/hip_runtime.h>
#include <math.h>

// ---------------------------------------------------------------------------
// GAT 3-layer net. R12 = exact revert to R10 (best verified: 374 us).
// R11 post-mortem: folding attn dots as 16 extra GEMM columns cost a full
// A-sweep per m-tile (+12 MB FETCH, -6% occupancy) -> +16 us. Reverted.
// R10 configuration:
//  - BK=64 128x128 bf16 MFMA GEMM, global_load_lds w=16, XOR LDS swizzle
//    (SQ_LDS_BANK_CONFLICT == 0), XCD-aware 1D grid swizzle.
//  - H features fp8-e4m3 (halves gather traffic); Y linear path bf16.
//  - attn3 fused into layer-3 GEMM epilogue; mega-prep single launch.
// ---------------------------------------------------------------------------

__device__ __forceinline__ float leaky(float x){ return x > 0.f ? x : 0.2f * x; }

__device__ __forceinline__ float bf2f(unsigned short u){
  union { unsigned int i; float f; } v; v.i = ((unsigned int)u) << 16; return v.f;
}
__device__ __forceinline__ unsigned short f2bf(float f){
  union { float f; unsigned int i; } v; v.f = f;
  unsigned int r = v.i + 0x7FFF + ((v.i >> 16) & 1);   // RNE
  return (unsigned short)(r >> 16);
}
__device__ __forceinline__ float4 loadbf4(const unsigned short* p){
  ushort4 u = *(const ushort4*)p;
  return make_float4(bf2f(u.x), bf2f(u.y), bf2f(u.z), bf2f(u.w));
}

// ---- fp8 e4m3 helpers (HW cvt; self-consistent round-trip) ----
typedef __attribute__((ext_vector_type(2))) float f2v;
__device__ __forceinline__ unsigned char f2fp8(float x){
  int v = __builtin_amdgcn_cvt_pk_fp8_f32(x, x, 0, false);
  return (unsigned char)(v & 0xff);
}
__device__ __forceinline__ float4 fp8x4(unsigned int u){
  f2v a = __builtin_amdgcn_cvt_pk_f32_fp8((int)u, false);
  f2v b = __builtin_amdgcn_cvt_pk_f32_fp8((int)u, true);
  return make_float4(a.x, a.y, b.x, b.y);
}

// ---------------- mega prep kernel ----------------
__device__ __forceinline__ void tr_tile(const float* __restrict__ W,
                                        unsigned short* __restrict__ Wt,
                                        int K, int N, int rowOff, int lb,
                                        unsigned short tile[32][33]){
  int gx = K >> 5;
  int bk = (lb % gx) << 5;
  int bn = (lb / gx) << 5;
  int tx = threadIdx.x & 31;
  int ty = threadIdx.x >> 5;
#pragma unroll
  for (int r = 0; r < 32; r += 8)
    tile[ty + r][tx] = f2bf(W[(size_t)(bk + ty + r) * N + bn + tx]);
  __syncthreads();
#pragma unroll
  for (int r = 0; r < 32; r += 8)
    Wt[(size_t)(rowOff + bn + ty + r) * K + bk + tx] = tile[tx][ty + r];
}

__global__ __launch_bounds__(256) void k_prep(
    const float* __restrict__ W1, const float* __restrict__ Wl1,
    const float* __restrict__ W2, const float* __restrict__ Wl2,
    const float* __restrict__ W3, const float* __restrict__ Wl3,
    const float* __restrict__ bl3,
    const float* __restrict__ nf, const int* __restrict__ ei,
    unsigned short* __restrict__ Wc1, unsigned short* __restrict__ Wc2,
    unsigned short* __restrict__ Bt3, float* __restrict__ biasc,
    unsigned short* __restrict__ Abf1, unsigned short* __restrict__ Abf2,
    int* __restrict__ deg, int Mpad, int N, int E)
{
  __shared__ unsigned short tile[32][33];
  int lb = blockIdx.x;
  if (lb < 512){ tr_tile(W1, Wc1, 512, 1024, 0, lb, tile); return; }
  lb -= 512;
  if (lb < 512){ tr_tile(Wl1, Wc1, 512, 1024, 1024, lb, tile); return; }
  lb -= 512;
  if (lb < 1024){ tr_tile(W2, Wc2, 1024, 1024, 0, lb, tile); return; }
  lb -= 1024;
  if (lb < 1024){ tr_tile(Wl2, Wc2, 1024, 1024, 1024, lb, tile); return; }
  lb -= 1024;
  if (lb < 512){              // w3fill: Bt3[128][1024] + biasc[48]
    int idx = lb * 256 + threadIdx.x;
    if (idx < 48) biasc[idx] = (idx >= 36 && idx < 42) ? bl3[idx - 36] : 0.f;
    int n = idx >> 10, k = idx & 1023;
    float v = 0.f;
    if (n < 36) v = W3[(size_t)k * 36 + n];
    else if (n < 42) v = Wl3[(size_t)k * 6 + (n - 36)];
    Bt3[idx] = f2bf(v);
    return;
  }
  lb -= 512;
  int cvtBlocks = Mpad >> 1;
  if (lb < cvtBlocks){        // nf fp32 [N,512] -> Abf1 bf16 [Mpad,512]
    int idx = lb * 256 + threadIdx.x;
    int e = idx << 2;
    int row = e >> 9;
    ushort4 o;
    if (row < N){
      float4 v = *(const float4*)(nf + (size_t)row * 512 + (e & 511));
      o.x = f2bf(v.x); o.y = f2bf(v.y); o.z = f2bf(v.z); o.w = f2bf(v.w);
    } else { o.x = o.y = o.z = o.w = 0; }
    *(ushort4*)(Abf1 + e) = o;
    return;
  }
  lb -= cvtBlocks;
  int padBlocks = Mpad - N;
  if (lb < padBlocks){        // zero Abf2 rows N..Mpad
    int idx = lb * 256 + threadIdx.x;
    ushort4 z; z.x = z.y = z.z = z.w = 0;
    *(ushort4*)(Abf2 + (size_t)N * 1024 + (size_t)idx * 4) = z;
    return;
  }
  lb -= padBlocks;
  int e = lb * 256 + threadIdx.x;   // degree count
  if (e < E) atomicAdd(&deg[ei[E + e]], 1);
}

// ---------------- CSR scan + scatter ----------------
__global__ void k_scan(const int* __restrict__ deg, int* __restrict__ rp,
                       int* __restrict__ cur, int n){
  __shared__ int part[1024];
  int t = threadIdx.x;
  int K = (n + 1023) >> 10;
  int vals[16];
  int start = t * K;
  int local = 0;
  for (int j = 0; j < K; j++){
    int idx = start + j;
    int v = (idx < n) ? deg[idx] : 0;
    vals[j] = local;
    local += v;
  }
  part[t] = local;
  __syncthreads();
  for (int off = 1; off < 1024; off <<= 1){
    int v = (t >= off) ? part[t - off] : 0;
    __syncthreads();
    part[t] += v;
    __syncthreads();
  }
  int base = part[t] - local;
  for (int j = 0; j < K; j++){
    int idx = start + j;
    if (idx < n){ rp[idx] = base + vals[j]; cur[idx] = base + vals[j]; }
  }
  if (t == 1023) rp[n] = part[1023];
}

__global__ void k_scatter(const int* __restrict__ ei, int* __restrict__ cur,
                          int* __restrict__ col, int E){
  int e = blockIdx.x * blockDim.x + threadIdx.x;
  if (e < E){
    int s = ei[e], d = ei[E + e];
    int p = atomicAdd(&cur[d], 1);
    col[p] = s;
  }
}

// ---------------- bf16 MFMA GEMM, 128x128 tile, BK=64, LDS XOR swizzle ------
typedef __attribute__((ext_vector_type(8))) short bf8_t;
typedef __attribute__((ext_vector_type(4))) float f4_t;

__device__ __forceinline__ void async16(const unsigned short* g, unsigned short* l){
  __builtin_amdgcn_global_load_lds(
      (const __attribute__((address_space(1))) void*)g,
      (__attribute__((address_space(3))) void*)l, 16, 0, 0);
}

// grid: 8 * Gm * Ntiles (1D); xcd = b&7 owns m-tiles [xcd*Gm, ...)
// fpOut=0 (layers 1/2, Ntot=2048): bn<1024 -> outH fp8; bn>=1024 -> outY bf16+bias
// fpOut=1 (layer 3, Ntot=48): outF fp32 + bias; fused attn3 dots via LDS.
__global__ __launch_bounds__(256) void k_mfma_gemm(
    const unsigned short* __restrict__ A,
    const unsigned short* __restrict__ Bt,
    const float* __restrict__ bias,
    unsigned char* __restrict__ outH,
    unsigned short* __restrict__ outY,
    float* __restrict__ outF,
    const float* __restrict__ as3, const float* __restrict__ ad3,
    float* __restrict__ als3, float* __restrict__ ald3,
    int M, int K, int Ntot, int Mtiles, int Gm, int fpOut)
{
  __shared__ unsigned short SM[2 * 8192];        // 32 KB total
  unsigned short* Asm = SM;                      // 16 KB (two 32-k planes)
  unsigned short* Bsm = SM + 8192;               // 16 KB
  int b = blockIdx.x;
  int xcd = b & 7;
  int j = b >> 3;
  int mloc = j % Gm;
  int n = j / Gm;
  int mtile = xcd * Gm + mloc;
  if (mtile >= Mtiles) return;
  int bm = mtile * 128, bn = n * 128;

  int t = threadIdx.x;
  int w = t >> 6, lane = t & 63;
  int wm = (w >> 1) * 64, wn = (w & 1) * 64;
  int lr = lane & 15, lq = lane >> 4;

  f4_t acc[4][4] = {};

  int srow = lane >> 2;                                   // 0..15 in chunk
  int scol = (((lane & 3) ^ ((lane >> 3) & 3)) << 3);     // swizzled k-chunk
  int sw   = (lr >> 1) & 3;                               // read-side swizzle

  for (int k0 = 0; k0 < K; k0 += 64){
#pragma unroll
    for (int h = 0; h < 2; h++){
#pragma unroll
      for (int r = 0; r < 2; r++){
        int c = r * 4 + w;
        async16(A + (size_t)(bm + c * 16 + srow) * K + k0 + h * 32 + scol,
                &Asm[h * 4096 + c * 512]);
        async16(Bt + (size_t)(bn + c * 16 + srow) * K + k0 + h * 32 + scol,
                &Bsm[h * 4096 + c * 512]);
      }
    }
    __syncthreads();
#pragma unroll
    for (int h = 0; h < 2; h++){
      bf8_t a[4], bfr[4];
#pragma unroll
      for (int i = 0; i < 4; i++)
        a[i] = *(const bf8_t*)&Asm[h * 4096 + (wm + i * 16 + lr) * 32 + (lq ^ sw) * 8];
#pragma unroll
      for (int i = 0; i < 4; i++)
        bfr[i] = *(const bf8_t*)&Bsm[h * 4096 + (wn + i * 16 + lr) * 32 + (lq ^ sw) * 8];
#pragma unroll
      for (int mi = 0; mi < 4; mi++)
#pragma unroll
        for (int ni = 0; ni < 4; ni++)
          acc[mi][ni] = __builtin_amdgcn_mfma_f32_16x16x32_bf16(a[mi], bfr[ni], acc[mi][ni], 0, 0, 0);
    }
    __syncthreads();
  }

  if (fpOut){
    // layer 3: bn==0, Ntot=48. Stage rows into LDS (stride 49) for fused dots.
    float* cl = (float*)SM;
#pragma unroll
    for (int mi = 0; mi < 4; mi++){
#pragma unroll
      for (int ni = 0; ni < 4; ni++){
        int colg = wn + ni * 16 + lr;
        if (colg >= Ntot) continue;
        float bv = bias[colg];
#pragma unroll
        for (int rg = 0; rg < 4; rg++){
          int rowl = wm + mi * 16 + lq * 4 + rg;
          int rowg = bm + rowl;
          float v = acc[mi][ni][rg] + bv;
          cl[rowl * 49 + colg] = v;
          if (rowg < M) outF[(size_t)rowg * Ntot + colg] = v;
        }
      }
    }
    __syncthreads();
    for (int task = t; task < 128 * 6; task += 256){
      int row = task / 6, h = task - row * 6;
      int rowg = bm + row;
      if (rowg < M){
        float s = 0.f, d = 0.f;
#pragma unroll
        for (int c = 0; c < 6; c++){
          float v = cl[row * 49 + h * 6 + c];
          s += v * as3[h * 6 + c];
          d += v * ad3[h * 6 + c];
        }
        als3[rowg * 6 + h] = s;
        ald3[rowg * 6 + h] = d;
      }
    }
  } else if (bn < 1024){
    // H half -> fp8
#pragma unroll
    for (int mi = 0; mi < 4; mi++){
#pragma unroll
      for (int ni = 0; ni < 4; ni++){
        int colg = bn + wn + ni * 16 + lr;
#pragma unroll
        for (int rg = 0; rg < 4; rg++){
          int rowg = bm + wm + mi * 16 + lq * 4 + rg;
          if (rowg < M) outH[(size_t)rowg * 1024 + colg] = f2fp8(acc[mi][ni][rg]);
        }
      }
    }
  } else {
    // Y half -> bf16 + bias
#pragma unroll
    for (int mi = 0; mi < 4; mi++){
#pragma unroll
      for (int ni = 0; ni < 4; ni++){
        int colg = bn + wn + ni * 16 + lr - 1024;
        float bv = bias[colg];
#pragma unroll
        for (int rg = 0; rg < 4; rg++){
          int rowg = bm + wm + mi * 16 + lq * 4 + rg;
          if (rowg < M) outY[(size_t)rowg * 1024 + colg] = f2bf(acc[mi][ni][rg] + bv);
        }
      }
    }
  }
}

// ---------------- attention dots (layers 1/2), H fp8 ----------------
__global__ __launch_bounds__(256) void k_attn_dots(const unsigned char* __restrict__ Hq,
                                                   const float* __restrict__ a_s,
                                                   const float* __restrict__ a_d,
                                                   float* __restrict__ als,
                                                   float* __restrict__ ald, int N){
  int i = blockIdx.x;
  int t = threadIdx.x;
  unsigned int u = *(const unsigned int*)(Hq + (size_t)i * 1024 + t * 4);
  float4 hv = fp8x4(u);
  float4 sv = ((const float4*)a_s)[t];
  float4 dv = ((const float4*)a_d)[t];
  float ps = hv.x * sv.x + hv.y * sv.y + hv.z * sv.z + hv.w * sv.w;
  float pd = hv.x * dv.x + hv.y * dv.y + hv.z * dv.z + hv.w * dv.w;
#pragma unroll
  for (int off = 32; off >= 1; off >>= 1){
    ps += __shfl_down(ps, off);
    pd += __shfl_down(pd, off);
  }
  if ((t & 63) == 0){
    int w = t >> 6;
    als[i * 4 + w] = ps;
    ald[i * 4 + w] = pd;
  }
}

// ---------------- GAT aggregation (layers 1/2): fp8 H gather + bf16 Y ------
__global__ __launch_bounds__(256) void k_agg(const unsigned char* __restrict__ Hq,
                                             const unsigned short* __restrict__ Y,
                                             unsigned short* __restrict__ Yout,
                                             const float* __restrict__ bias,
                                             const float* __restrict__ als,
                                             const float* __restrict__ ald,
                                             const int* __restrict__ rp,
                                             const int* __restrict__ col){
  int i = blockIdx.x;
  int t = threadIdx.x;
  int lane = t & 63;
  int w = t >> 6;
  int ro = rp[i];
  int deg = rp[i + 1] - ro;
  __shared__ float sm[4], ss[4];
  __shared__ float s_alpha[64][4];
  __shared__ int s_src[64];

  float aldw = ald[i * 4 + w];
  float eself = leaky(als[i * 4 + w] + aldw);
  float m = eself;
  float s = (lane == 0) ? 1.f : 0.f;
  for (int e = lane; e < deg; e += 64){
    int src = col[ro + e];
    float ev = leaky(als[src * 4 + w] + aldw);
    float M = fmaxf(m, ev);
    s = s * __expf(m - M) + __expf(ev - M);
    m = M;
  }
#pragma unroll
  for (int off = 32; off >= 1; off >>= 1){
    float mo = __shfl_down(m, off);
    float so = __shfl_down(s, off);
    float M = fmaxf(m, mo);
    s = s * __expf(m - M) + so * __expf(mo - M);
    m = M;
  }
  if (lane == 0){ sm[w] = m; ss[w] = s; }
  __syncthreads();

  int head = t >> 6;
  float mh = sm[head];
  float inv = 1.f / (ss[head] + 1e-16f);
  float4 acc = loadbf4(Y + (size_t)i * 1024 + t * 4);
  float4 bb  = *(const float4*)(bias + t * 4);
  acc.x += bb.x; acc.y += bb.y; acc.z += bb.z; acc.w += bb.w;
  float aself = __expf(leaky(als[i * 4 + head] + ald[i * 4 + head]) - mh) * inv;
  {
    float4 hv = fp8x4(*(const unsigned int*)(Hq + (size_t)i * 1024 + t * 4));
    acc.x += aself * hv.x; acc.y += aself * hv.y;
    acc.z += aself * hv.z; acc.w += aself * hv.w;
  }
  for (int base = 0; base < deg; base += 64){
    __syncthreads();
    if (t < 64 && base + t < deg){
      int src = col[ro + base + t];
      s_src[t] = src;
#pragma unroll
      for (int hh = 0; hh < 4; hh++){
        s_alpha[t][hh] = __expf(leaky(als[src * 4 + hh] + ald[i * 4 + hh]) - sm[hh])
                         / (ss[hh] + 1e-16f);
      }
    }
    __syncthreads();
    int nn = min(64, deg - base);
    for (int e = 0; e < nn; e++){
      float a = s_alpha[e][head];
      float4 hv = fp8x4(*(const unsigned int*)(Hq + (size_t)s_src[e] * 1024 + t * 4));
      acc.x += a * hv.x; acc.y += a * hv.y; acc.z += a * hv.z; acc.w += a * hv.w;
    }
  }
  acc.x = acc.x > 0.f ? acc.x : expm1f(acc.x);
  acc.y = acc.y > 0.f ? acc.y : expm1f(acc.y);
  acc.z = acc.z > 0.f ? acc.z : expm1f(acc.z);
  acc.w = acc.w > 0.f ? acc.w : expm1f(acc.w);
  ushort4 o;
  o.x = f2bf(acc.x); o.y = f2bf(acc.y); o.z = f2bf(acc.z); o.w = f2bf(acc.w);
  *(ushort4*)(Yout + (size_t)i * 1024 + t * 4) = o;
}

// ---------------- layer 3: GAT(mean heads) + b3 + lin3 + log_softmax ----------------
__global__ __launch_bounds__(64) void k_layer3(const float* __restrict__ comb,
                                               const float* __restrict__ als,
                                               const float* __restrict__ ald,
                                               const float* __restrict__ b3,
                                               const int* __restrict__ rp,
                                               const int* __restrict__ col,
                                               float* __restrict__ out){
  int i = blockIdx.x;
  int lane = threadIdx.x;
  int ro = rp[i], deg = rp[i + 1] - ro;
  float aldv[6], m[6], s[6];
#pragma unroll
  for (int h = 0; h < 6; h++){
    aldv[h] = ald[i * 6 + h];
    float e = leaky(als[i * 6 + h] + aldv[h]);
    m[h] = e;
    s[h] = (lane == 0) ? 1.f : 0.f;
  }
  for (int e = lane; e < deg; e += 64){
    int src = col[ro + e];
#pragma unroll
    for (int h = 0; h < 6; h++){
      float ev = leaky(als[src * 6 + h] + aldv[h]);
      float M = fmaxf(m[h], ev);
      s[h] = s[h] * __expf(m[h] - M) + __expf(ev - M);
      m[h] = M;
    }
  }
#pragma unroll
  for (int off = 32; off >= 1; off >>= 1){
#pragma unroll
    for (int h = 0; h < 6; h++){
      float mo = __shfl_down(m[h], off);
      float so = __shfl_down(s[h], off);
      float M = fmaxf(m[h], mo);
      s[h] = s[h] * __expf(m[h] - M) + so * __expf(mo - M);
      m[h] = M;
    }
  }
#pragma unroll
  for (int h = 0; h < 6; h++){ m[h] = __shfl(m[h], 0); s[h] = __shfl(s[h], 0); }

  __shared__ float o36[36];
  __shared__ float o6[6];
  if (lane < 36){
    int hh = lane / 6, cc = lane - hh * 6;
    float inv = 1.f / (s[hh] + 1e-16f);
    float acc = __expf(leaky(als[i * 6 + hh] + aldv[hh]) - m[hh]) * inv
                * comb[(size_t)i * 48 + hh * 6 + cc];
    for (int e = 0; e < deg; e++){
      int src = col[ro + e];
      float a = __expf(leaky(als[src * 6 + hh] + aldv[hh]) - m[hh]) * inv;
      acc += a * comb[(size_t)src * 48 + hh * 6 + cc];
    }
    o36[lane] = acc;
  }
  __syncthreads();
  if (lane < 6){
    float v = 0.f;
#pragma unroll
    for (int h = 0; h < 6; h++) v += o36[h * 6 + lane];
    o6[lane] = v * (1.f / 6.f) + b3[lane] + comb[(size_t)i * 48 + 36 + lane];
  }
  __syncthreads();
  if (lane == 0){
    float mx = o6[0];
    for (int c = 1; c < 6; c++) mx = fmaxf(mx, o6[c]);
    float se = 0.f;
    for (int c = 0; c < 6; c++) se += __expf(o6[c] - mx);
    float lse = logf(se);
    for (int c = 0; c < 6; c++) out[(size_t)i * 6 + c] = o6[c] - mx - lse;
  }
}

// ---------------------------------------------------------------------------
extern "C" void kernel_launch(void* const* d_in, const int* in_sizes, int n_in,
                              void* d_out, int out_size, void* d_ws, size_t ws_size,
                              hipStream_t stream){
  const float* nf  = (const float*)d_in[0];
  const int*   ei  = (const int*)d_in[1];
  const float* W1  = (const float*)d_in[2];
  const float* as1 = (const float*)d_in[3];
  const float* ad1 = (const float*)d_in[4];
  const float* b1  = (const float*)d_in[5];
  const float* Wl1 = (const float*)d_in[6];
  const float* bl1 = (const float*)d_in[7];
  const float* W2  = (const float*)d_in[8];
  const float* as2 = (const float*)d_in[9];
  const float* ad2 = (const float*)d_in[10];
  const float* b2  = (const float*)d_in[11];
  const float* Wl2 = (const float*)d_in[12];
  const float* bl2 = (const float*)d_in[13];
  const float* W3  = (const float*)d_in[14];
  const float* as3 = (const float*)d_in[15];
  const float* ad3 = (const float*)d_in[16];
  const float* b3  = (const float*)d_in[17];
  const float* Wl3 = (const float*)d_in[18];
  const float* bl3 = (const float*)d_in[19];
  float* out = (float*)d_out;

  const int N = in_sizes[0] / 512;   // 10000
  const int E = in_sizes[1] / 2;     // 160000
  const int Mpad = ((N + 127) / 128) * 128;   // 10112
  const int Mtiles = Mpad / 128;              // 79
  const int Gm = (Mtiles + 7) / 8;            // 10

  char* ws = (char*)d_ws;
  size_t off = 0;
  auto alloc = [&](size_t bytes) -> char* {
    char* p = ws + off;
    off += (bytes + 255) & ~(size_t)255;
    return p;
  };
  unsigned short* Abf1 = (unsigned short*)alloc((size_t)Mpad * 512 * 2);
  unsigned short* Abf2 = (unsigned short*)alloc((size_t)Mpad * 1024 * 2);
  unsigned char*  Hq   = (unsigned char*)alloc((size_t)N * 1024);
  unsigned short* Ybf  = (unsigned short*)alloc((size_t)N * 1024 * 2);
  float* comb   = (float*)alloc((size_t)N * 48 * 4);
  float* als    = (float*)alloc((size_t)N * 8 * 4);
  float* ald    = (float*)alloc((size_t)N * 8 * 4);
  float* biasc  = (float*)alloc(48 * 4);
  int* deg      = (int*)alloc((size_t)N * 4);
  int* rp       = (int*)alloc((size_t)(N + 1) * 4);
  int* cur      = (int*)alloc((size_t)N * 4);
  int* colx     = (int*)alloc((size_t)E * 4);
  unsigned short* Wc1 = (unsigned short*)alloc((size_t)2048 * 512 * 2);
  unsigned short* Wc2 = (unsigned short*)alloc((size_t)2048 * 1024 * 2);
  unsigned short* Bt3 = (unsigned short*)alloc((size_t)128 * 1024 * 2);

  hipMemsetAsync(deg, 0, (size_t)N * 4, stream);

  int prepBlocks = 512 + 512 + 1024 + 1024 + 512 + (Mpad >> 1) + (Mpad - N)
                 + (E + 255) / 256;
  k_prep<<<prepBlocks, 256, 0, stream>>>(W1, Wl1, W2, Wl2, W3, Wl3, bl3,
                                         nf, ei, Wc1, Wc2, Bt3, biasc,
                                         Abf1, Abf2, deg, Mpad, N, E);
  k_scan   <<<1, 1024, 0, stream>>>(deg, rp, cur, N);
  k_scatter<<<(E + 255) / 256, 256, 0, stream>>>(ei, cur, colx, E);

  int blocksL = 8 * Gm * 16;
  int blocks3 = 8 * Gm * 1;

  // layer 1
  k_mfma_gemm<<<blocksL, 256, 0, stream>>>(Abf1, Wc1, bl1, Hq, Ybf, nullptr,
                                           nullptr, nullptr, nullptr, nullptr,
                                           N, 512, 2048, Mtiles, Gm, 0);
  k_attn_dots<<<N, 256, 0, stream>>>(Hq, as1, ad1, als, ald, N);
  k_agg<<<N, 256, 0, stream>>>(Hq, Ybf, Abf2, b1, als, ald, rp, colx);

  // layer 2
  k_mfma_gemm<<<blocksL, 256, 0, stream>>>(Abf2, Wc2, bl2, Hq, Ybf, nullptr,
                                           nullptr, nullptr, nullptr, nullptr,
                                           N, 1024, 2048, Mtiles, Gm, 0);
  k_attn_dots<<<N, 256, 0, stream>>>(Hq, as2, ad2, als, ald, N);
  k_agg<<<N, 256, 0, stream>>>(Hq, Ybf, Abf2, b2, als, ald, rp, colx);

  // layer 3 (attn3 fused into GEMM epilogue)
  k_mfma_gemm<<<blocks3, 256, 0, stream>>>(Abf2, Bt3, biasc, nullptr, nullptr, comb,
                                           as3, ad3, als, ald,
                                           N, 1024, 48, Mtiles, Gm, 1);
  k_layer3<<<N, 64, 0, stream>>>(comb, als, ald, b3, rp, colx, out);
}